// Round 8
// baseline (221.918 us; speedup 1.0000x reference)
//
#include <hip/hip_runtime.h>

#define N_NODES 50000
#define E_EDGES 800000
#define D_DIM   128
#define LN_EPS  1e-5f
#define SCAN_BLOCKS 196   // ceil(50000/256)
#define HIST_BLOCKS 3125  // 800000/256 exactly
#define GEMM_BLOCKS 782   // ceil(50000/64)

// fp32 -> bf16 (round to nearest even), stored as raw ushort
__device__ inline unsigned short f2b(float f) {
    unsigned int u = __float_as_uint(f);
    unsigned int r = u + 0x7FFFu + ((u >> 16) & 1u);
    return (unsigned short)(r >> 16);
}

// ---------------- K_prep: zero count, transpose W_lin ----------------------
__global__ void k_prep(const float* __restrict__ W, float* __restrict__ Wt,
                       int* __restrict__ count) {
    int i = blockIdx.x * 256 + threadIdx.x;
    if (i < N_NODES) count[i] = 0;
    if (i < 16384) {                          // Wt[d][o] = W[o][d]
        int d = i >> 7, o = i & 127;
        Wt[i] = W[o * 128 + d];
    }
}

// ---------------- K1: fused [gemm blocks] + [hist blocks] ------------------
// GEMM blocks first (long pole starts immediately); hist blocks trail.
// 64 rows/block, 8x4 outputs/thread: halves W-staging + barriers per output;
// x-row LDS reads are lane-invariant broadcasts (free).
__global__ __launch_bounds__(256, 3) void k_gemm_hist(
        const float* __restrict__ x, const float* __restrict__ Wt,
        const float* __restrict__ Wa, const int* __restrict__ dst,
        int* __restrict__ count, unsigned short* __restrict__ hb,
        float* __restrict__ ssrc, float* __restrict__ sdst) {
    __shared__ float xl[64 * 128];   // 32 KB: 64 x-rows
    __shared__ float wl[32 * 128];   // 16 KB: one 32-deep W chunk
    const int tid = threadIdx.x;

    if (blockIdx.x >= GEMM_BLOCKS) {
        int e = (blockIdx.x - GEMM_BLOCKS) * 256 + tid;  // exactly 800000
        atomicAdd(&count[dst[e]], 1);
        return;
    }

    const int n0 = blockIdx.x * 64;

    // stage 64 x-rows: 2048 float4, 8 per thread (coalesced)
    #pragma unroll
    for (int i = 0; i < 8; ++i) {
        int idx = i * 256 + tid;
        int row = idx >> 5, d4 = idx & 31;
        int n = n0 + row; if (n >= N_NODES) n = N_NODES - 1;
        ((float4*)xl)[idx] = ((const float4*)(x + (size_t)n * 128))[d4];
    }

    const int c = tid & 31;    // cols 4c..4c+3
    const int r = tid >> 5;    // rows 8r..8r+7
    float4 acc[8];
    #pragma unroll
    for (int j = 0; j < 8; ++j) acc[j] = make_float4(0.f, 0.f, 0.f, 0.f);

    for (int p = 0; p < 4; ++p) {            // four 32-deep K chunks
        __syncthreads();                     // WAR (covers xl RAW at p=0)
        #pragma unroll
        for (int i = 0; i < 4; ++i) {
            int idx = i * 256 + tid;         // 1024 float4 = 32x128 fp32
            ((float4*)wl)[idx] = ((const float4*)(Wt + (size_t)p * 32 * 128))[idx];
        }
        __syncthreads();                     // RAW
        #pragma unroll
        for (int d4 = 0; d4 < 8; ++d4) {
            float4 wv[4];
            #pragma unroll
            for (int k = 0; k < 4; ++k)
                wv[k] = *(const float4*)&wl[(4 * d4 + k) * 128 + 4 * c];
            #pragma unroll
            for (int j = 0; j < 8; ++j) {
                float4 xv = *(const float4*)&xl[(8 * r + j) * 128 + p * 32 + 4 * d4];
                #pragma unroll
                for (int k = 0; k < 4; ++k) {
                    float xs = (&xv.x)[k];
                    acc[j].x += xs * wv[k].x; acc[j].y += xs * wv[k].y;
                    acc[j].z += xs * wv[k].z; acc[j].w += xs * wv[k].w;
                }
            }
        }
    }

    float as0 = Wa[4*c],     as1 = Wa[4*c+1],     as2 = Wa[4*c+2],     as3 = Wa[4*c+3];
    float ad0 = Wa[128+4*c], ad1 = Wa[128+4*c+1], ad2 = Wa[128+4*c+2], ad3 = Wa[128+4*c+3];
    #pragma unroll
    for (int j = 0; j < 8; ++j) {
        int n = n0 + 8 * r + j;
        float ps = acc[j].x*as0 + acc[j].y*as1 + acc[j].z*as2 + acc[j].w*as3;
        float pd = acc[j].x*ad0 + acc[j].y*ad1 + acc[j].z*ad2 + acc[j].w*ad3;
        #pragma unroll
        for (int off = 16; off >= 1; off >>= 1) {   // reduce over 32 c-lanes
            ps += __shfl_xor(ps, off);
            pd += __shfl_xor(pd, off);
        }
        if (n < N_NODES) {
            ushort4 b4;
            b4.x = f2b(acc[j].x); b4.y = f2b(acc[j].y);
            b4.z = f2b(acc[j].z); b4.w = f2b(acc[j].w);
            *(ushort4*)&hb[(size_t)n * 128 + 4 * c] = b4;
            if (c == 0) { ssrc[n] = ps; sdst[n] = pd; }
        }
    }
}

// ---------------- K2b.1: per-block exclusive scan (256 elems/block) --------
__global__ __launch_bounds__(256) void k_scan1(const int* __restrict__ count,
                                               int* __restrict__ rowptr,
                                               int* __restrict__ bsum) {
    __shared__ int wsum[4];
    const int tid  = threadIdx.x;
    const int lane = tid & 63, w = tid >> 6;
    int i = blockIdx.x * 256 + tid;
    int v = (i < N_NODES) ? count[i] : 0;
    int sc = v;
    #pragma unroll
    for (int off = 1; off < 64; off <<= 1) {
        int t = __shfl_up(sc, off);
        if (lane >= off) sc += t;
    }
    if (lane == 63) wsum[w] = sc;
    __syncthreads();
    if (tid == 0) {
        int s0 = wsum[0], s1 = wsum[1], s2 = wsum[2], s3 = wsum[3];
        wsum[0] = 0; wsum[1] = s0; wsum[2] = s0 + s1; wsum[3] = s0 + s1 + s2;
        bsum[blockIdx.x] = s0 + s1 + s2 + s3;
    }
    __syncthreads();
    if (i < N_NODES) rowptr[i] = sc - v + wsum[w];   // block-local exclusive
}

// ---------------- K2b.2: exclusive scan of the 196 block sums --------------
__global__ __launch_bounds__(256) void k_scan2(int* __restrict__ bsum) {
    __shared__ int wsum[4];
    const int tid  = threadIdx.x;
    const int lane = tid & 63, w = tid >> 6;
    int v = (tid < SCAN_BLOCKS) ? bsum[tid] : 0;
    int sc = v;
    #pragma unroll
    for (int off = 1; off < 64; off <<= 1) {
        int t = __shfl_up(sc, off);
        if (lane >= off) sc += t;
    }
    if (lane == 63) wsum[w] = sc;
    __syncthreads();
    if (tid == 0) {
        int s0 = wsum[0], s1 = wsum[1], s2 = wsum[2];
        wsum[3] = s0 + s1 + s2; wsum[2] = s0 + s1; wsum[1] = s0; wsum[0] = 0;
    }
    __syncthreads();
    if (tid < SCAN_BLOCKS) bsum[tid] = sc - v + wsum[w];
}

// ---------------- K2c: scatter (src, exp(score)) pairs into CSR order ------
// count (degrees, already consumed by scan1) doubles as the cursor via
// atomicSub -> positions fill end-1..0 within each segment (order-free sum).
__global__ void k_scatter(const int* __restrict__ src, const int* __restrict__ dst,
                          const float* __restrict__ ssrc, const float* __restrict__ sdst,
                          const int* __restrict__ rowptr, const int* __restrict__ bsum,
                          int* __restrict__ count, uint2* __restrict__ sev) {
    int e = blockIdx.x * 256 + threadIdx.x;   // exactly 800000 threads
    int s  = src[e];
    int dv = dst[e];
    float sc = ssrc[s] + sdst[dv];
    sc = sc >= 0.f ? sc : 0.2f * sc;          // LeakyReLU(0.2)
    float ex = __expf(sc);
    int pos = rowptr[dv] + bsum[dv >> 8] + (atomicSub(&count[dv], 1) - 1);
    sev[pos] = make_uint2((unsigned int)s, __float_as_uint(ex));
}

// ---------------- K3: per-node gather-aggregate + fused residual+LN --------
// One wave per node; lane l handles dims 2l, 2l+1. Scores precomputed, so
// per edge: 8B broadcast load + coalesced h-row load + 1 add + 2 FMA.
__global__ __launch_bounds__(256) void k_gather(
        const int* __restrict__ rowptr, const int* __restrict__ bsum,
        const uint2* __restrict__ sev,
        const unsigned short* __restrict__ hb, const float* __restrict__ x,
        const float* __restrict__ scale, const float* __restrict__ bias,
        float* __restrict__ out) {
    int n    = blockIdx.x * 4 + (threadIdx.x >> 6);
    int lane = threadIdx.x & 63;
    int beg = rowptr[n] + bsum[n >> 8];
    int end = (n == N_NODES - 1) ? E_EDGES : rowptr[n + 1] + bsum[(n + 1) >> 8];

    float a0 = 0.f, a1 = 0.f, b0 = 0.f, b1 = 0.f, den = 0.f;

    int i = beg;
    for (; i + 3 < end; i += 4) {             // 4-edge unroll: 4 h-loads in flight
        uint2 p0 = sev[i],     p1 = sev[i + 1];
        uint2 p2 = sev[i + 2], p3 = sev[i + 3];
        unsigned int u0 = *(const unsigned int*)&hb[(size_t)p0.x * 128 + 2 * lane];
        unsigned int u1 = *(const unsigned int*)&hb[(size_t)p1.x * 128 + 2 * lane];
        unsigned int u2 = *(const unsigned int*)&hb[(size_t)p2.x * 128 + 2 * lane];
        unsigned int u3 = *(const unsigned int*)&hb[(size_t)p3.x * 128 + 2 * lane];
        float ex0 = __uint_as_float(p0.y), ex1 = __uint_as_float(p1.y);
        float ex2 = __uint_as_float(p2.y), ex3 = __uint_as_float(p3.y);
        den += (ex0 + ex1) + (ex2 + ex3);
        a0 += ex0 * __uint_as_float(u0 << 16);
        a1 += ex0 * __uint_as_float(u0 & 0xFFFF0000u);
        b0 += ex1 * __uint_as_float(u1 << 16);
        b1 += ex1 * __uint_as_float(u1 & 0xFFFF0000u);
        a0 += ex2 * __uint_as_float(u2 << 16);
        a1 += ex2 * __uint_as_float(u2 & 0xFFFF0000u);
        b0 += ex3 * __uint_as_float(u3 << 16);
        b1 += ex3 * __uint_as_float(u3 & 0xFFFF0000u);
    }
    for (; i < end; ++i) {
        uint2 p0 = sev[i];
        unsigned int u0 = *(const unsigned int*)&hb[(size_t)p0.x * 128 + 2 * lane];
        float ex0 = __uint_as_float(p0.y);
        den += ex0;
        a0 += ex0 * __uint_as_float(u0 << 16);
        a1 += ex0 * __uint_as_float(u0 & 0xFFFF0000u);
    }
    a0 += b0; a1 += b1;

    float inv_d = 1.f / (den > 0.f ? den : 1.f);
    size_t base = (size_t)n * 128 + 2 * lane;
    float2 xv = *(const float2*)&x[base];
    float r0 = a0 * inv_d + xv.x;
    float r1 = a1 * inv_d + xv.y;

    float sum = r0 + r1;
    #pragma unroll
    for (int off = 32; off >= 1; off >>= 1) sum += __shfl_xor(sum, off);
    float mu = sum * (1.f / 128.f);
    float d0 = r0 - mu, d1 = r1 - mu;
    float ss = d0 * d0 + d1 * d1;
    #pragma unroll
    for (int off = 32; off >= 1; off >>= 1) ss += __shfl_xor(ss, off);
    float inv = rsqrtf(ss * (1.f / 128.f) + LN_EPS);
    float o0 = d0 * inv * scale[2 * lane]     + bias[2 * lane];
    float o1 = d1 * inv * scale[2 * lane + 1] + bias[2 * lane + 1];
    *(float2*)&out[base] = make_float2(o0, o1);
}

extern "C" void kernel_launch(void* const* d_in, const int* in_sizes, int n_in,
                              void* d_out, int out_size, void* d_ws, size_t ws_size,
                              hipStream_t stream) {
    const float* x        = (const float*)d_in[0];
    const float* W_lin    = (const float*)d_in[1];
    const float* W_attn   = (const float*)d_in[2];
    const float* ln_scale = (const float*)d_in[3];
    const float* ln_bias  = (const float*)d_in[4];
    const int*   edge     = (const int*)d_in[5];
    const int*   e_src    = edge;
    const int*   e_dst    = edge + E_EDGES;
    float* out = (float*)d_out;

    char* ws = (char*)d_ws;
    unsigned short* hb = (unsigned short*)(ws);   // 12,800,000 B
    float* Wt     = (float*)(ws + 12800000);      //     65,536 B
    float* ssrc   = (float*)(ws + 12865536);      //    200,000 B
    float* sdst   = (float*)(ws + 13065536);      //    200,000 B
    int*   count  = (int*)  (ws + 13265536);      //    200,000 B (degrees, then cursor)
    int*   rowptr = (int*)  (ws + 13465536);      //    200,016 B (padded)
    int*   bsum   = (int*)  (ws + 13665552);      //        800 B (padded)
    uint2* sev    = (uint2*)(ws + 13666352);      //  6,400,000 B  (~20.1 MB)

    k_prep     <<<SCAN_BLOCKS, 256, 0, stream>>>(W_lin, Wt, count);
    k_gemm_hist<<<GEMM_BLOCKS + HIST_BLOCKS, 256, 0, stream>>>(
                    x, Wt, W_attn, e_dst, count, hb, ssrc, sdst);
    k_scan1    <<<SCAN_BLOCKS, 256, 0, stream>>>(count, rowptr, bsum);
    k_scan2    <<<1,    256, 0, stream>>>(bsum);
    k_scatter  <<<HIST_BLOCKS, 256, 0, stream>>>(e_src, e_dst, ssrc, sdst,
                                                 rowptr, bsum, count, sev);
    k_gather   <<<12500, 256, 0, stream>>>(rowptr, bsum, sev, hb, x,
                                           ln_scale, ln_bias, out);
}

// Round 9
// 213.306 us; speedup vs baseline: 1.0404x; 1.0404x over previous
//
#include <hip/hip_runtime.h>

#define N_NODES 50000
#define E_EDGES 800000
#define D_DIM   128
#define LN_EPS  1e-5f
#define SCAN_BLOCKS 196   // ceil(50000/256)
#define HIST_BLOCKS 3125  // 800000/256 exactly
#define GEMM_BLOCKS 391   // ceil(50000/128)

// fp32 -> bf16 (round to nearest even), stored as raw ushort
__device__ inline unsigned short f2b(float f) {
    unsigned int u = __float_as_uint(f);
    unsigned int r = u + 0x7FFFu + ((u >> 16) & 1u);
    return (unsigned short)(r >> 16);
}

// ---------------- K_prep: zero count, transpose W_lin ----------------------
__global__ void k_prep(const float* __restrict__ W, float* __restrict__ Wt,
                       int* __restrict__ count) {
    int i = blockIdx.x * 256 + threadIdx.x;
    if (i < N_NODES) count[i] = 0;
    if (i < 16384) {                          // Wt[d][o] = W[o][d]
        int d = i >> 7, o = i & 127;
        Wt[i] = W[o * 128 + d];
    }
}

// ---------------- K1: fused [gemm blocks] + [hist blocks] ------------------
// 128x128 tile, 256 threads as 16x16: 8 rows x 8 cols per thread.
// Per d4-step: 16 ds_read_b128 feed 256 FMAs (ratio 16) -> VALU-bound.
// 80 KB LDS -> 2 blocks/CU. Hist blocks trail after the 391 GEMM blocks.
__global__ __launch_bounds__(256, 2) void k_gemm_hist(
        const float* __restrict__ x, const float* __restrict__ Wt,
        const float* __restrict__ Wa, const int* __restrict__ dst,
        int* __restrict__ count, unsigned short* __restrict__ hb,
        float* __restrict__ ssrc, float* __restrict__ sdst) {
    __shared__ float xl[128 * 128];  // 64 KB: 128 x-rows
    __shared__ float wl[32 * 128];   // 16 KB: one 32-deep W chunk
    const int tid = threadIdx.x;

    if (blockIdx.x >= GEMM_BLOCKS) {
        int e = (blockIdx.x - GEMM_BLOCKS) * 256 + tid;  // exactly 800000
        atomicAdd(&count[dst[e]], 1);
        return;
    }

    const int n0 = blockIdx.x * 128;

    // stage 128 x-rows: 4096 float4, 16 per thread (coalesced)
    #pragma unroll
    for (int i = 0; i < 16; ++i) {
        int idx = i * 256 + tid;
        int row = idx >> 5, c4 = idx & 31;
        int n = n0 + row; if (n >= N_NODES) n = N_NODES - 1;
        ((float4*)xl)[idx] = ((const float4*)(x + (size_t)n * 128))[c4];
    }

    const int c = tid & 15;    // col groups: 4c..4c+3 and 64+4c..64+4c+3
    const int r = tid >> 4;    // rows 8r..8r+7
    float4 accA[8], accB[8];
    #pragma unroll
    for (int j = 0; j < 8; ++j) {
        accA[j] = make_float4(0.f, 0.f, 0.f, 0.f);
        accB[j] = make_float4(0.f, 0.f, 0.f, 0.f);
    }

    for (int p = 0; p < 4; ++p) {            // four 32-deep K chunks
        __syncthreads();                     // WAR (covers xl RAW at p=0)
        #pragma unroll
        for (int i = 0; i < 4; ++i) {
            int idx = i * 256 + tid;         // 1024 float4 = 32x128 fp32
            ((float4*)wl)[idx] = ((const float4*)(Wt + (size_t)p * 32 * 128))[idx];
        }
        __syncthreads();                     // RAW
        #pragma unroll
        for (int d4 = 0; d4 < 8; ++d4) {
            float4 wvA[4], wvB[4];
            #pragma unroll
            for (int k = 0; k < 4; ++k) {
                wvA[k] = *(const float4*)&wl[(4 * d4 + k) * 128 + 4 * c];
                wvB[k] = *(const float4*)&wl[(4 * d4 + k) * 128 + 64 + 4 * c];
            }
            #pragma unroll
            for (int j = 0; j < 8; ++j) {
                float4 xv = *(const float4*)&xl[(8 * r + j) * 128 + p * 32 + 4 * d4];
                #pragma unroll
                for (int k = 0; k < 4; ++k) {
                    float xs = (&xv.x)[k];
                    accA[j].x += xs * wvA[k].x; accA[j].y += xs * wvA[k].y;
                    accA[j].z += xs * wvA[k].z; accA[j].w += xs * wvA[k].w;
                    accB[j].x += xs * wvB[k].x; accB[j].y += xs * wvB[k].y;
                    accB[j].z += xs * wvB[k].z; accB[j].w += xs * wvB[k].w;
                }
            }
        }
    }

    float asA0 = Wa[4*c],    asA1 = Wa[4*c+1],    asA2 = Wa[4*c+2],    asA3 = Wa[4*c+3];
    float asB0 = Wa[64+4*c], asB1 = Wa[64+4*c+1], asB2 = Wa[64+4*c+2], asB3 = Wa[64+4*c+3];
    float adA0 = Wa[128+4*c],    adA1 = Wa[128+4*c+1],    adA2 = Wa[128+4*c+2],    adA3 = Wa[128+4*c+3];
    float adB0 = Wa[128+64+4*c], adB1 = Wa[128+64+4*c+1], adB2 = Wa[128+64+4*c+2], adB3 = Wa[128+64+4*c+3];
    #pragma unroll
    for (int j = 0; j < 8; ++j) {
        int n = n0 + 8 * r + j;
        float ps = accA[j].x*asA0 + accA[j].y*asA1 + accA[j].z*asA2 + accA[j].w*asA3
                 + accB[j].x*asB0 + accB[j].y*asB1 + accB[j].z*asB2 + accB[j].w*asB3;
        float pd = accA[j].x*adA0 + accA[j].y*adA1 + accA[j].z*adA2 + accA[j].w*adA3
                 + accB[j].x*adB0 + accB[j].y*adB1 + accB[j].z*adB2 + accB[j].w*adB3;
        #pragma unroll
        for (int off = 1; off < 16; off <<= 1) {   // reduce over the 16 c-lanes
            ps += __shfl_xor(ps, off);
            pd += __shfl_xor(pd, off);
        }
        if (n < N_NODES) {
            ushort4 b4;
            b4.x = f2b(accA[j].x); b4.y = f2b(accA[j].y);
            b4.z = f2b(accA[j].z); b4.w = f2b(accA[j].w);
            *(ushort4*)&hb[(size_t)n * 128 + 4 * c] = b4;
            b4.x = f2b(accB[j].x); b4.y = f2b(accB[j].y);
            b4.z = f2b(accB[j].z); b4.w = f2b(accB[j].w);
            *(ushort4*)&hb[(size_t)n * 128 + 64 + 4 * c] = b4;
            if (c == 0) { ssrc[n] = ps; sdst[n] = pd; }
        }
    }
}

// ---------------- K2b.1: per-block exclusive scan (256 elems/block) --------
__global__ __launch_bounds__(256) void k_scan1(const int* __restrict__ count,
                                               int* __restrict__ rowptr,
                                               int* __restrict__ bsum) {
    __shared__ int wsum[4];
    const int tid  = threadIdx.x;
    const int lane = tid & 63, w = tid >> 6;
    int i = blockIdx.x * 256 + tid;
    int v = (i < N_NODES) ? count[i] : 0;
    int sc = v;
    #pragma unroll
    for (int off = 1; off < 64; off <<= 1) {
        int t = __shfl_up(sc, off);
        if (lane >= off) sc += t;
    }
    if (lane == 63) wsum[w] = sc;
    __syncthreads();
    if (tid == 0) {
        int s0 = wsum[0], s1 = wsum[1], s2 = wsum[2], s3 = wsum[3];
        wsum[0] = 0; wsum[1] = s0; wsum[2] = s0 + s1; wsum[3] = s0 + s1 + s2;
        bsum[blockIdx.x] = s0 + s1 + s2 + s3;
    }
    __syncthreads();
    if (i < N_NODES) rowptr[i] = sc - v + wsum[w];   // block-local exclusive
}

// ---------------- K2b.2: exclusive scan of the 196 block sums --------------
__global__ __launch_bounds__(256) void k_scan2(int* __restrict__ bsum) {
    __shared__ int wsum[4];
    const int tid  = threadIdx.x;
    const int lane = tid & 63, w = tid >> 6;
    int v = (tid < SCAN_BLOCKS) ? bsum[tid] : 0;
    int sc = v;
    #pragma unroll
    for (int off = 1; off < 64; off <<= 1) {
        int t = __shfl_up(sc, off);
        if (lane >= off) sc += t;
    }
    if (lane == 63) wsum[w] = sc;
    __syncthreads();
    if (tid == 0) {
        int s0 = wsum[0], s1 = wsum[1], s2 = wsum[2];
        wsum[3] = s0 + s1 + s2; wsum[2] = s0 + s1; wsum[1] = s0; wsum[0] = 0;
    }
    __syncthreads();
    if (tid < SCAN_BLOCKS) bsum[tid] = sc - v + wsum[w];
}

// ---------------- K2c: scatter (src, exp(score)) pairs into CSR order ------
__global__ void k_scatter(const int* __restrict__ src, const int* __restrict__ dst,
                          const float* __restrict__ ssrc, const float* __restrict__ sdst,
                          const int* __restrict__ rowptr, const int* __restrict__ bsum,
                          int* __restrict__ count, uint2* __restrict__ sev) {
    int e = blockIdx.x * 256 + threadIdx.x;   // exactly 800000 threads
    int s  = src[e];
    int dv = dst[e];
    float sc = ssrc[s] + sdst[dv];
    sc = sc >= 0.f ? sc : 0.2f * sc;          // LeakyReLU(0.2)
    float ex = __expf(sc);
    int pos = rowptr[dv] + bsum[dv >> 8] + (atomicSub(&count[dv], 1) - 1);
    sev[pos] = make_uint2((unsigned int)s, __float_as_uint(ex));
}

// ---------------- K3: per-node gather-aggregate + fused residual+LN --------
// One wave per node; lane l handles dims 2l, 2l+1. 8-edge unroll keeps 8
// independent h-row loads in flight.
__global__ __launch_bounds__(256) void k_gather(
        const int* __restrict__ rowptr, const int* __restrict__ bsum,
        const uint2* __restrict__ sev,
        const unsigned short* __restrict__ hb, const float* __restrict__ x,
        const float* __restrict__ scale, const float* __restrict__ bias,
        float* __restrict__ out) {
    int n    = blockIdx.x * 4 + (threadIdx.x >> 6);
    int lane = threadIdx.x & 63;
    int beg = rowptr[n] + bsum[n >> 8];
    int end = (n == N_NODES - 1) ? E_EDGES : rowptr[n + 1] + bsum[(n + 1) >> 8];

    float a0 = 0.f, a1 = 0.f, b0 = 0.f, b1 = 0.f, den = 0.f;

    int i = beg;
    for (; i + 7 < end; i += 8) {             // 8 h-loads in flight
        uint2 p[8];
        unsigned int u[8];
        #pragma unroll
        for (int q = 0; q < 8; ++q) p[q] = sev[i + q];
        #pragma unroll
        for (int q = 0; q < 8; ++q)
            u[q] = *(const unsigned int*)&hb[(size_t)p[q].x * 128 + 2 * lane];
        #pragma unroll
        for (int q = 0; q < 8; q += 2) {
            float ex0 = __uint_as_float(p[q].y), ex1 = __uint_as_float(p[q + 1].y);
            den += ex0 + ex1;
            a0 += ex0 * __uint_as_float(u[q] << 16);
            a1 += ex0 * __uint_as_float(u[q] & 0xFFFF0000u);
            b0 += ex1 * __uint_as_float(u[q + 1] << 16);
            b1 += ex1 * __uint_as_float(u[q + 1] & 0xFFFF0000u);
        }
    }
    for (; i < end; ++i) {
        uint2 p0 = sev[i];
        unsigned int u0 = *(const unsigned int*)&hb[(size_t)p0.x * 128 + 2 * lane];
        float ex0 = __uint_as_float(p0.y);
        den += ex0;
        a0 += ex0 * __uint_as_float(u0 << 16);
        a1 += ex0 * __uint_as_float(u0 & 0xFFFF0000u);
    }
    a0 += b0; a1 += b1;

    float inv_d = 1.f / (den > 0.f ? den : 1.f);
    size_t base = (size_t)n * 128 + 2 * lane;
    float2 xv = *(const float2*)&x[base];
    float r0 = a0 * inv_d + xv.x;
    float r1 = a1 * inv_d + xv.y;

    float sum = r0 + r1;
    #pragma unroll
    for (int off = 32; off >= 1; off >>= 1) sum += __shfl_xor(sum, off);
    float mu = sum * (1.f / 128.f);
    float d0 = r0 - mu, d1 = r1 - mu;
    float ss = d0 * d0 + d1 * d1;
    #pragma unroll
    for (int off = 32; off >= 1; off >>= 1) ss += __shfl_xor(ss, off);
    float inv = rsqrtf(ss * (1.f / 128.f) + LN_EPS);
    float o0 = d0 * inv * scale[2 * lane]     + bias[2 * lane];
    float o1 = d1 * inv * scale[2 * lane + 1] + bias[2 * lane + 1];
    *(float2*)&out[base] = make_float2(o0, o1);
}

extern "C" void kernel_launch(void* const* d_in, const int* in_sizes, int n_in,
                              void* d_out, int out_size, void* d_ws, size_t ws_size,
                              hipStream_t stream) {
    const float* x        = (const float*)d_in[0];
    const float* W_lin    = (const float*)d_in[1];
    const float* W_attn   = (const float*)d_in[2];
    const float* ln_scale = (const float*)d_in[3];
    const float* ln_bias  = (const float*)d_in[4];
    const int*   edge     = (const int*)d_in[5];
    const int*   e_src    = edge;
    const int*   e_dst    = edge + E_EDGES;
    float* out = (float*)d_out;

    char* ws = (char*)d_ws;
    unsigned short* hb = (unsigned short*)(ws);   // 12,800,000 B
    float* Wt     = (float*)(ws + 12800000);      //     65,536 B
    float* ssrc   = (float*)(ws + 12865536);      //    200,000 B
    float* sdst   = (float*)(ws + 13065536);      //    200,000 B
    int*   count  = (int*)  (ws + 13265536);      //    200,000 B (degrees, then cursor)
    int*   rowptr = (int*)  (ws + 13465536);      //    200,016 B (padded)
    int*   bsum   = (int*)  (ws + 13665552);      //        800 B (padded)
    uint2* sev    = (uint2*)(ws + 13666352);      //  6,400,000 B  (~20.1 MB)

    k_prep     <<<SCAN_BLOCKS, 256, 0, stream>>>(W_lin, Wt, count);
    k_gemm_hist<<<GEMM_BLOCKS + HIST_BLOCKS, 256, 0, stream>>>(
                    x, Wt, W_attn, e_dst, count, hb, ssrc, sdst);
    k_scan1    <<<SCAN_BLOCKS, 256, 0, stream>>>(count, rowptr, bsum);
    k_scan2    <<<1,    256, 0, stream>>>(bsum);
    k_scatter  <<<HIST_BLOCKS, 256, 0, stream>>>(e_src, e_dst, ssrc, sdst,
                                                 rowptr, bsum, count, sev);
    k_gather   <<<12500, 256, 0, stream>>>(rowptr, bsum, sev, hb, x,
                                           ln_scale, ln_bias, out);
}